// Round 18
// baseline (277.417 us; speedup 1.0000x reference)
//
#include <hip/hip_runtime.h>
#include <hip/hip_bf16.h>
#include <math.h>

typedef __bf16 bf16_t;
typedef __bf16 bf16x8 __attribute__((ext_vector_type(8)));
typedef __bf16 bf16x4 __attribute__((ext_vector_type(4)));
typedef float  f32x4  __attribute__((ext_vector_type(4)));

// Problem geometry (fixed): x[4][2048][1024], w1[1024][4096], w2[4096][1024]
#define NROWS 8192   // 4*2048
#define HD    1024
#define DFF   4096
#define HKEEP 513    // h-columns materialized (Hermitian: only h<=512 independent)

typedef __attribute__((address_space(1))) const void* gas_cptr;
typedef __attribute__((address_space(3))) void* las_ptr;

__device__ __forceinline__ void gload_lds16(const void* g, void* l) {
  __builtin_amdgcn_global_load_lds((gas_cptr)g, (las_ptr)l, 16, 0, 0);
}

template <int N> __device__ __forceinline__ void vmw() {
  if      constexpr (N==4)  asm volatile("s_waitcnt vmcnt(4)"  ::: "memory");
  else if constexpr (N==6)  asm volatile("s_waitcnt vmcnt(6)"  ::: "memory");
}

// ---------------- transpose + f32->bf16 convert (w1 -> [DFF][H], w2 -> [H][DFF])
__global__ __launch_bounds__(256) void transpose_to_bf16(
    const float* __restrict__ in, bf16_t* __restrict__ out, int R, int C)
{
  __shared__ float tile[32][33];
  const int bx = blockIdx.x, by = blockIdx.y;
  const int tx = threadIdx.x, ty = threadIdx.y;
  #pragma unroll
  for (int i = ty; i < 32; i += 8)
    tile[i][tx] = in[(size_t)(by*32 + i)*C + bx*32 + tx];
  __syncthreads();
  #pragma unroll
  for (int i = ty; i < 32; i += 8)
    out[(size_t)(bx*32 + i)*R + by*32 + tx] = (bf16_t)tile[tx][i];
}

// ---------------- fused: 1024-pt FFT along h for 16 rows/block, real input,
// HERMITIAN PAIR-PACKED: rows (2q,2q+1) -> one complex row z = a + i*b.
// Truncated transposed spectrum stored as bf16.
#define RPB 16
#define LDW 1036   // padded row stride (f32)
__global__ __launch_bounds__(512) void fft_h_t(
    const float* __restrict__ x, bf16_t* __restrict__ reT, bf16_t* __restrict__ imT)
{
  __shared__ float sre[8*LDW], sim[8*LDW], twc[512], tws[512];
  const int t = threadIdx.x;
  const int row0 = blockIdx.x * RPB;
  {
    float sv, cv; sincosf(-6.28318530717958647692f * (float)t * (1.0f/1024.0f), &sv, &cv);
    twc[t] = cv; tws[t] = sv;   // t in [0,512)
  }
  #pragma unroll
  for (int q = 0; q < 4; ++q) {
    const int i = t + 512*q;            // 0..2047
    const int pr = i >> 8;              // packed row 0..7
    const int c4 = i & 255;
    float4 vr = *(const float4*)(x + (size_t)(row0 + 2*pr    )*HD + c4*4);
    float4 vi = *(const float4*)(x + (size_t)(row0 + 2*pr + 1)*HD + c4*4);
    *(float4*)&sre[pr*LDW + c4*4] = vr;
    *(float4*)&sim[pr*LDW + c4*4] = vi;
  }
  __syncthreads();
  const int b0i = __brev((unsigned)t) >> 22;
  const int b1i = __brev((unsigned)(t + 512)) >> 22;
  float rv[32];
  #pragma unroll
  for (int q = 0; q < 8; ++q) {
    rv[4*q]   = sre[q*LDW + b0i];
    rv[4*q+1] = sre[q*LDW + b1i];
    rv[4*q+2] = sim[q*LDW + b0i];
    rv[4*q+3] = sim[q*LDW + b1i];
  }
  __syncthreads();
  #pragma unroll
  for (int q = 0; q < 8; ++q) {
    sre[q*LDW + t]       = rv[4*q];
    sre[q*LDW + t + 512] = rv[4*q+1];
    sim[q*LDW + t]       = rv[4*q+2];
    sim[q*LDW + t + 512] = rv[4*q+3];
  }
  __syncthreads();
  for (int s = 0; s < 10; ++s) {
    const int half = 1 << s;
    const int j    = t & (half - 1);
    const int ib   = ((t >> s) << (s + 1)) | j;
    const int ti2  = j << (9 - s);
    const float wc = twc[ti2], ws = tws[ti2];
    #pragma unroll
    for (int q = 0; q < 8; ++q) {
      float* pr = &sre[q*LDW]; float* pi = &sim[q*LDW];
      const float r1 = pr[ib],      i1v = pi[ib];
      const float r2 = pr[ib+half], i2v = pi[ib+half];
      const float tr = r2*wc - i2v*ws;
      const float ti = r2*ws + i2v*wc;
      pr[ib]      = r1 + tr; pi[ib]      = i1v + ti;
      pr[ib+half] = r1 - tr; pi[ib+half] = i1v - ti;
    }
    __syncthreads();
  }
  const int tx = t & 15, th = t >> 4;    // tx: real row 0..15, th 0..31
  const int q  = tx >> 1, par = tx & 1;
  #pragma unroll
  for (int hh = 0; hh < 17; ++hh) {
    const int h = hh*32 + th;
    if (h < HKEEP) {
      const int mh = (1024 - h) & 1023;
      const float zr = sre[q*LDW + h],  zi = sim[q*LDW + h];
      const float mr = sre[q*LDW + mh], mi = sim[q*LDW + mh];
      float orr, oii;
      if (par == 0) { orr = 0.5f*(zr + mr); oii = 0.5f*(zi - mi); }
      else          { orr = 0.5f*(zi + mi); oii = 0.5f*(mr - zr); }
      reT[(size_t)h*NROWS + row0 + tx] = (bf16_t)orr;
      imT[(size_t)h*NROWS + row0 + tx] = (bf16_t)oii;
    }
  }
}

// ---------------- 2048-pt FFT along s, one (h, batch) column per block; bf16 in/out.
__global__ __launch_bounds__(256) void fft_s_col(
    const bf16_t* __restrict__ reT, const bf16_t* __restrict__ imT,
    bf16_t* __restrict__ fTb)
{
  __shared__ float sre[2048], sim[2048], twc[1024], tws[1024];
  const int t = threadIdx.x;
  const int h = blockIdx.x;           // 0..512
  const int batch = blockIdx.y;       // 0..3
  const size_t base = (size_t)h * NROWS + batch * 2048;
  for (int k = t; k < 1024; k += 256) {
    float sv, cv; sincosf(-6.28318530717958647692f * (float)k * (1.0f/2048.0f), &sv, &cv);
    twc[k] = cv; tws[k] = sv;
  }
  #pragma unroll
  for (int q = 0; q < 8; ++q) {
    const int i = t + 256*q;
    const int src = __brev((unsigned)i) >> 21;   // 11-bit bit reversal
    sre[i] = (float)reT[base + src];
    sim[i] = (float)imT[base + src];
  }
  __syncthreads();
  for (int s = 0; s < 11; ++s) {
    const int half = 1 << s;
    #pragma unroll
    for (int q = 0; q < 4; ++q) {
      const int b  = t + 256*q;
      const int j  = b & (half - 1);
      const int ib = ((b >> s) << (s + 1)) | j;
      const int ti2 = j << (10 - s);
      const float wc = twc[ti2], ws = tws[ti2];
      const float r1 = sre[ib],       i1v = sim[ib];
      const float r2 = sre[ib+half],  i2v = sim[ib+half];
      const float tr = r2*wc - i2v*ws;
      const float ti = r2*ws + i2v*wc;
      sre[ib]      = r1 + tr; sim[ib]      = i1v + ti;
      sre[ib+half] = r1 - tr; sim[ib+half] = i1v - ti;
    }
    __syncthreads();
  }
  #pragma unroll
  for (int q = 0; q < 8; ++q) {
    const int i = t + 256*q;
    fTb[base + i] = (bf16_t)sre[i];
  }
}

// ---------------- fused: untranspose + Hermitian mirror + x residual + LN1 -> xn
// r18: vectorized gather - both the direct slice fTb[h][r0..r0+15] and the
// mirrored slice (reverse-contiguous) are 32B runs -> 2 x bf16x8 loads per
// h-slot instead of 16 scalar loads. Slot map h = t + 256c keeps LDS scatter
// at 2-way banks. rl0==0 wrap (4 blocks) falls back to scalar (block-uniform).
#define FLD 1028   // padded row stride (f32)
__global__ __launch_bounds__(256) void fuse_umadd_ln1(
    const bf16_t* __restrict__ fTb, const float* __restrict__ x,
    const float* __restrict__ gw, const float* __restrict__ gb,
    bf16_t* __restrict__ xn)
{
  __shared__ float tile[16*FLD];
  __shared__ float mrow[16], vrow[16];
  const int t = threadIdx.x;
  const int r0 = blockIdx.x * 16;
  const int batch = r0 >> 11;            // 16 | 2048 -> uniform per block
  const int rl0 = r0 & 2047;             // s index of row 0 (block-uniform)
  #pragma unroll
  for (int c = 0; c < 4; ++c) {
    const int h = t + 256*c;             // 0..1023
    bf16_t vals[16];                     // vals[rb] = fourier term for row r0+rb
    if (h <= 512) {
      const bf16_t* src = fTb + (size_t)h*NROWS + r0;
      *(bf16x8*)&vals[0] = *(const bf16x8*)(src);
      *(bf16x8*)&vals[8] = *(const bf16x8*)(src + 8);
    } else {
      const int hm = 1024 - h;           // 1..511
      const bf16_t* base = fTb + (size_t)hm*NROWS + (batch << 11);
      if (rl0 == 0) {
        vals[0] = base[0];
        #pragma unroll
        for (int rb = 1; rb < 16; ++rb) vals[rb] = base[2048 - rb];
      } else {
        // sp(rb) = 2048 - rl0 - rb, contiguous run [2048-rl0-15, 2048-rl0]
        bf16_t tmp[16];
        *(bf16x8*)&tmp[0] = *(const bf16x8*)(base + (2048 - rl0 - 15));
        *(bf16x8*)&tmp[8] = *(const bf16x8*)(base + (2048 - rl0 - 7));
        #pragma unroll
        for (int rb = 0; rb < 16; ++rb) vals[rb] = tmp[15 - rb];
      }
    }
    #pragma unroll
    for (int rb = 0; rb < 16; ++rb)
      tile[rb*FLD + h] = (float)vals[rb];
  }
  __syncthreads();
  #pragma unroll
  for (int rr = 0; rr < 16; ++rr) {
    float4 xv = *(const float4*)(x + (size_t)(r0+rr)*HD + t*4);
    float4 tv = *(float4*)&tile[rr*FLD + t*4];
    tv.x += xv.x; tv.y += xv.y; tv.z += xv.z; tv.w += xv.w;
    *(float4*)&tile[rr*FLD + t*4] = tv;
  }
  __syncthreads();
  {
    const int r = t >> 4, i = t & 15;
    float s = 0.f, s2 = 0.f;
    #pragma unroll
    for (int k = 0; k < 64; ++k) {
      const float v = tile[r*FLD + i + 16*k];
      s += v; s2 += v*v;
    }
    #pragma unroll
    for (int o = 8; o > 0; o >>= 1) { s += __shfl_xor(s, o); s2 += __shfl_xor(s2, o); }
    if (i == 0) {
      const float mu = s * (1.0f/1024.0f);
      mrow[r] = mu;
      vrow[r] = rsqrtf(s2 * (1.0f/1024.0f) - mu*mu + 1e-5f);
    }
  }
  __syncthreads();
  const float4 wv = *(const float4*)(gw + t*4);
  const float4 bv = *(const float4*)(gb + t*4);
  #pragma unroll
  for (int rr = 0; rr < 16; ++rr) {
    const float mu = mrow[rr], rs = vrow[rr];
    float4 tv = *(float4*)&tile[rr*FLD + t*4];
    bf16x4 o;
    o[0] = (bf16_t)((tv.x-mu)*rs*wv.x + bv.x);
    o[1] = (bf16_t)((tv.y-mu)*rs*wv.y + bv.y);
    o[2] = (bf16_t)((tv.z-mu)*rs*wv.z + bv.z);
    o[3] = (bf16_t)((tv.w-mu)*rs*wv.w + bv.w);
    *(bf16x4*)(xn + (size_t)(r0+rr)*HD + t*4) = o;
  }
}

// ---------------- LayerNorm over H=1024, bf16 in, fp32 out (LN2)
__global__ __launch_bounds__(256) void layernorm_b2f(
    const bf16_t* __restrict__ in, const float* __restrict__ gw,
    const float* __restrict__ gb, float* __restrict__ of)
{
  __shared__ float red[8];
  const size_t row = blockIdx.x;
  const int t = threadIdx.x;
  bf16x4 v4 = *(const bf16x4*)(in + row*HD + t*4);
  const float vx = (float)v4[0], vy = (float)v4[1], vz = (float)v4[2], vw = (float)v4[3];
  float s = vx + vy + vz + vw;
  #pragma unroll
  for (int o = 32; o > 0; o >>= 1) s += __shfl_xor(s, o);
  if ((t & 63) == 0) red[t >> 6] = s;
  __syncthreads();
  const float mu = (red[0]+red[1]+red[2]+red[3]) * (1.0f/1024.0f);
  const float dx = vx-mu, dy = vy-mu, dz = vz-mu, dw = vw-mu;
  float sq = dx*dx + dy*dy + dz*dz + dw*dw;
  #pragma unroll
  for (int o = 32; o > 0; o >>= 1) sq += __shfl_xor(sq, o);
  if ((t & 63) == 0) red[4 + (t >> 6)] = sq;
  __syncthreads();
  const float var  = (red[4]+red[5]+red[6]+red[7]) * (1.0f/1024.0f);
  const float rstd = rsqrtf(var + 1e-5f);
  const float4 wv = *(const float4*)(gw + t*4);
  const float4 bv = *(const float4*)(gb + t*4);
  float4 o;
  o.x = dx*rstd*wv.x + bv.x;
  o.y = dy*rstd*wv.y + bv.y;
  o.z = dz*rstd*wv.z + bv.z;
  o.w = dw*rstd*wv.w + bv.w;
  *(float4*)(of + row*HD + t*4) = o;
}

// fast GELU (tanh form via exp2); |err| vs erf-GELU ~1e-3 << 0.1075 threshold
__device__ __forceinline__ float gelu_fast(float v) {
  const float u  = 0.7978845608028654f * v * (1.0f + 0.044715f * v * v);
  const float e  = exp2f(-2.8853900817779268f * u);   // exp(-2u)
  return v / (1.0f + e);                               // v * sigmoid(2u)
}

// ---------------- 8-phase 256x(NQ*128) bf16 MFMA GEMM (frozen: r14 best-measured)
template <int NQ, bool GELU_OUT>
__global__ __launch_bounds__(512, 2) void gemm8r(
    const bf16_t* __restrict__ A,     // [M][K]
    const bf16_t* __restrict__ Bt,    // [N][K]
    const float*  __restrict__ bias,  // [N]
    const bf16_t* __restrict__ resid, // [M][N] (only when !GELU_OUT)
    bf16_t* __restrict__ outB,
    int M, int N, int K, int gx)
{
  __shared__ bf16_t As[2][2][128*64];
  __shared__ bf16_t Bs[2][2][NQ*64*64];

  const int tid  = threadIdx.x;
  const int wave = tid >> 6, lane = tid & 63;
  const int wr = wave >> 2, wc = wave & 3;   // 2x4 waves
  const int lr = lane & 15, lkg = lane >> 4;

  const int nwg = gridDim.x;
  const int sid = (blockIdx.x & 7) * (nwg >> 3) + (blockIdx.x >> 3);
  const int bx = sid % gx, by = sid / gx;
  const int brow = by * 256, bcol = bx * (NQ*128);

  const int rl = lane >> 3;                  // 0..7
  const int sg = (lane & 7) ^ rl;            // pre-swizzled source k-group

  auto stageA = [&](int b, int mh, int tt) {
    #pragma unroll
    for (int l = 0; l < 2; ++l) {
      const int row = brow + l*128 + mh*64 + wave*8 + rl;
      gload_lds16(A + (size_t)row * K + tt*64 + sg*8,
                  &As[b][mh][(l*64 + wave*8)*64]);
    }
  };
  auto stageB = [&](int b, int nh, int tt) {
    #pragma unroll
    for (int l = 0; l < NQ; ++l) {
      const int rho = l*64 + wave*8 + rl;
      const int wcs = rho / (NQ*16), r = rho % (NQ*16);
      const int row = bcol + wcs*(NQ*32) + nh*(NQ*16) + r;
      gload_lds16(Bt + (size_t)row * K + tt*64 + sg*8,
                  &Bs[b][nh][(l*64 + wave*8)*64]);
    }
  };

  f32x4 acc[8][2*NQ] = {};
  bf16x8 af[4][2];          // current A-half fragments
  bf16x8 bq[2][NQ][2];      // BOTH B-half fragments resident (NH static index)

  const int NT = K >> 6;
  const int NI = NT >> 1;
  constexpr int WT = (NQ==2) ? 6 : 4;   // counted wait: 3 stage-halves in flight

  #define PHASE(BUF, MH, NH, DOA, DOB, STG, DOW) do { \
    if constexpr (DOA) { \
      _Pragma("unroll") for (int m = 0; m < 4; ++m) { \
      _Pragma("unroll") for (int ks = 0; ks < 2; ++ks) \
        af[m][ks] = *(const bf16x8*)&As[BUF][MH][(wr*64 + m*16 + lr)*64 + (((lkg + ks*4) ^ (lr & 7)) << 3)]; } \
    } \
    if constexpr (DOB) { \
      _Pragma("unroll") for (int n = 0; n < NQ; ++n) { \
      _Pragma("unroll") for (int ks = 0; ks < 2; ++ks) \
        bq[NH][n][ks] = *(const bf16x8*)&Bs[BUF][NH][(wc*(NQ*16) + n*16 + lr)*64 + (((lkg + ks*4) ^ (lr & 7)) << 3)]; } \
    } \
    STG; \
    __builtin_amdgcn_s_barrier(); \
    asm volatile("s_waitcnt lgkmcnt(0)" ::: "memory"); \
    __builtin_amdgcn_sched_barrier(0); \
    __builtin_amdgcn_s_setprio(1); \
    _Pragma("unroll") for (int m = 0; m < 4; ++m) { \
    _Pragma("unroll") for (int n = 0; n < NQ; ++n) { \
    _Pragma("unroll") for (int ks = 0; ks < 2; ++ks) \
      acc[(MH)*4+m][(NH)*NQ+n] = __builtin_amdgcn_mfma_f32_16x16x32_bf16(bq[NH][n][ks], af[m][ks], acc[(MH)*4+m][(NH)*NQ+n], 0, 0, 0); } } \
    __builtin_amdgcn_s_setprio(0); \
    if constexpr (DOW) vmw<WT>(); \
    __builtin_amdgcn_s_barrier(); \
  } while (0)

  // prologue: buf0 tile0 (Bh0,Ah0,Bh1,Ah1) + buf1 tile1 (Bh0,Ah0,Bh1)
  stageB(0,0,0); stageA(0,0,0); stageB(0,1,0); stageA(0,1,0);
  stageB(1,0,1); stageA(1,0,1); stageB(1,1,1);
  vmw<WT>();
  __builtin_amdgcn_s_barrier();

  for (int j = 0; j < NI; ++j) {
    const int c1 = 2*j + 1;
    const int n2 = (2*j + 2 < NT) ? 2*j + 2 : NT - 1;
    const int n3 = (2*j + 3 < NT) ? 2*j + 3 : NT - 1;
    PHASE(0, 0, 0, 1, 1, stageA(1,1,c1), false);   // p0
    PHASE(0, 0, 1, 0, 1, stageB(0,0,n2), false);   // p1
    PHASE(0, 1, 1, 1, 0, stageA(0,0,n2), false);   // p2
    PHASE(0, 1, 0, 0, 0, stageB(0,1,n2), true);    // p3  vmcnt(WT)
    PHASE(1, 0, 0, 1, 1, stageA(0,1,n2), false);   // p4
    PHASE(1, 0, 1, 0, 1, stageB(1,0,n3), false);   // p5
    PHASE(1, 1, 1, 1, 0, stageA(1,0,n3), false);   // p6
    PHASE(1, 1, 0, 0, 0, stageB(1,1,n3), true);    // p7  vmcnt(WT)
  }
  #undef PHASE

  // epilogue
  #pragma unroll
  for (int im = 0; im < 8; ++im) {
    const int row = brow + wr*128 + (im >> 2)*64 + (im & 3)*16 + lr;
    #pragma unroll
    for (int in = 0; in < 2*NQ; ++in) {
      const int col = bcol + wc*(NQ*32) + (in/NQ)*(NQ*16) + (in%NQ)*16 + lkg*4;
      const float4 bv4 = *(const float4*)(bias + col);
      float v0 = acc[im][in][0] + bv4.x;
      float v1 = acc[im][in][1] + bv4.y;
      float v2 = acc[im][in][2] + bv4.z;
      float v3 = acc[im][in][3] + bv4.w;
      bf16x4 o;
      if constexpr (GELU_OUT) {
        o[0] = (bf16_t)gelu_fast(v0); o[1] = (bf16_t)gelu_fast(v1);
        o[2] = (bf16_t)gelu_fast(v2); o[3] = (bf16_t)gelu_fast(v3);
      } else {
        bf16x4 rr = *(const bf16x4*)(resid + (size_t)row * N + col);
        o[0] = (bf16_t)(v0 + (float)rr[0]); o[1] = (bf16_t)(v1 + (float)rr[1]);
        o[2] = (bf16_t)(v2 + (float)rr[2]); o[3] = (bf16_t)(v3 + (float)rr[3]);
      }
      *(bf16x4*)(outB + (size_t)row * N + col) = o;
    }
  }
}

extern "C" void kernel_launch(void* const* d_in, const int* in_sizes, int n_in,
                              void* d_out, int out_size, void* d_ws, size_t ws_size,
                              hipStream_t stream) {
  const float* x    = (const float*)d_in[0];
  const float* ln1w = (const float*)d_in[1];
  const float* ln1b = (const float*)d_in[2];
  const float* ln2w = (const float*)d_in[3];
  const float* ln2b = (const float*)d_in[4];
  const float* w1   = (const float*)d_in[5];
  const float* b1   = (const float*)d_in[6];
  const float* w2   = (const float*)d_in[7];
  const float* b2   = (const float*)d_in[8];
  float* out = (float*)d_out;

  // workspace (peak < 128 MB, lifetimes checked):
  //  w1b [0,8M)  w2b [8,16M)                         (all steps)
  //  reTb [16,25M)  imTb [26,35M)  (bf16)            (steps 2-3)
  //  fTb  [36,45M)  (bf16)                           (steps 3-4)
  //  xn  [99,115M)                                   (steps 4-6, GEMM2 resid)
  //  hg  [16,80M)  (reuses reTb/imTb/fTb, all dead)  (steps 5-6)
  //  z   [80,96M)  (bf16 pre-LN2)                    (steps 6-7)
  char* ws = (char*)d_ws;
  bf16_t* w1b  = (bf16_t*)(ws);
  bf16_t* w2b  = (bf16_t*)(ws + (8u   << 20));
  bf16_t* reTb = (bf16_t*)(ws + (16u  << 20));
  bf16_t* imTb = (bf16_t*)(ws + (26u  << 20));
  bf16_t* fTb  = (bf16_t*)(ws + (36u  << 20));
  bf16_t* xn   = (bf16_t*)(ws + (99u  << 20));
  bf16_t* hg   = (bf16_t*)(ws + (16u  << 20));
  bf16_t* z    = (bf16_t*)(ws + (80u  << 20));

  // 1. weight transposes + bf16 conversion
  transpose_to_bf16<<<dim3(DFF/32, HD/32), dim3(32, 8), 0, stream>>>(w1, w1b, HD, DFF);
  transpose_to_bf16<<<dim3(HD/32, DFF/32), dim3(32, 8), 0, stream>>>(w2, w2b, DFF, HD);

  // 2. pair-packed FFT along h + transposed truncated store (bf16)
  fft_h_t<<<NROWS/RPB, 512, 0, stream>>>(x, reTb, imTb);

  // 3. FFT along s per (h<=512, batch) column; real part out (bf16)
  fft_s_col<<<dim3(513, 4), 256, 0, stream>>>(reTb, imTb, fTb);

  // 4. fused untranspose + mirror + x residual + LN1 -> xn (bf16, vector gather)
  fuse_umadd_ln1<<<NROWS/16, 256, 0, stream>>>(fTb, x, ln1w, ln1b, xn);

  // 5./6. FFN: 8-phase GEMMs (frozen); GEMM2 emits bf16 z
  gemm8r<2, true><<<(NROWS/256)*(DFF/256), 512, 0, stream>>>(
      xn, w1b, b1, nullptr, hg, NROWS, DFF, HD, DFF/256);
  gemm8r<1, false><<<(NROWS/256)*(HD/128), 512, 0, stream>>>(
      hg, w2b, b2, xn, z, NROWS, HD, DFF, HD/128);

  // 7. LN2: bf16 z -> fp32 out
  layernorm_b2f<<<NROWS, 256, 0, stream>>>(z, ln2w, ln2b, out);
}

// Round 19
// 276.652 us; speedup vs baseline: 1.0028x; 1.0028x over previous
//
#include <hip/hip_runtime.h>
#include <hip/hip_bf16.h>
#include <math.h>

typedef __bf16 bf16_t;
typedef __bf16 bf16x8 __attribute__((ext_vector_type(8)));
typedef __bf16 bf16x4 __attribute__((ext_vector_type(4)));
typedef float  f32x4  __attribute__((ext_vector_type(4)));

// Problem geometry (fixed): x[4][2048][1024], w1[1024][4096], w2[4096][1024]
#define NROWS 8192   // 4*2048
#define HD    1024
#define DFF   4096
#define HKEEP 513    // h-columns materialized (Hermitian: only h<=512 independent)

typedef __attribute__((address_space(1))) const void* gas_cptr;
typedef __attribute__((address_space(3))) void* las_ptr;

__device__ __forceinline__ void gload_lds16(const void* g, void* l) {
  __builtin_amdgcn_global_load_lds((gas_cptr)g, (las_ptr)l, 16, 0, 0);
}

template <int N> __device__ __forceinline__ void vmw() {
  if      constexpr (N==4)  asm volatile("s_waitcnt vmcnt(4)"  ::: "memory");
  else if constexpr (N==6)  asm volatile("s_waitcnt vmcnt(6)"  ::: "memory");
}

// ---------------- transpose + f32->bf16 convert (w1 -> [DFF][H], w2 -> [H][DFF])
__global__ __launch_bounds__(256) void transpose_to_bf16(
    const float* __restrict__ in, bf16_t* __restrict__ out, int R, int C)
{
  __shared__ float tile[32][33];
  const int bx = blockIdx.x, by = blockIdx.y;
  const int tx = threadIdx.x, ty = threadIdx.y;
  #pragma unroll
  for (int i = ty; i < 32; i += 8)
    tile[i][tx] = in[(size_t)(by*32 + i)*C + bx*32 + tx];
  __syncthreads();
  #pragma unroll
  for (int i = ty; i < 32; i += 8)
    out[(size_t)(bx*32 + i)*R + by*32 + tx] = (bf16_t)tile[tx][i];
}

// ---------------- fused: 1024-pt FFT along h for 16 rows/block, real input,
// HERMITIAN PAIR-PACKED: rows (2q,2q+1) -> one complex row z = a + i*b.
// Truncated transposed spectrum stored as bf16.
#define RPB 16
#define LDW 1036   // padded row stride (f32)
__global__ __launch_bounds__(512) void fft_h_t(
    const float* __restrict__ x, bf16_t* __restrict__ reT, bf16_t* __restrict__ imT)
{
  __shared__ float sre[8*LDW], sim[8*LDW], twc[512], tws[512];
  const int t = threadIdx.x;
  const int row0 = blockIdx.x * RPB;
  {
    float sv, cv; sincosf(-6.28318530717958647692f * (float)t * (1.0f/1024.0f), &sv, &cv);
    twc[t] = cv; tws[t] = sv;   // t in [0,512)
  }
  #pragma unroll
  for (int q = 0; q < 4; ++q) {
    const int i = t + 512*q;            // 0..2047
    const int pr = i >> 8;              // packed row 0..7
    const int c4 = i & 255;
    float4 vr = *(const float4*)(x + (size_t)(row0 + 2*pr    )*HD + c4*4);
    float4 vi = *(const float4*)(x + (size_t)(row0 + 2*pr + 1)*HD + c4*4);
    *(float4*)&sre[pr*LDW + c4*4] = vr;
    *(float4*)&sim[pr*LDW + c4*4] = vi;
  }
  __syncthreads();
  const int b0i = __brev((unsigned)t) >> 22;
  const int b1i = __brev((unsigned)(t + 512)) >> 22;
  float rv[32];
  #pragma unroll
  for (int q = 0; q < 8; ++q) {
    rv[4*q]   = sre[q*LDW + b0i];
    rv[4*q+1] = sre[q*LDW + b1i];
    rv[4*q+2] = sim[q*LDW + b0i];
    rv[4*q+3] = sim[q*LDW + b1i];
  }
  __syncthreads();
  #pragma unroll
  for (int q = 0; q < 8; ++q) {
    sre[q*LDW + t]       = rv[4*q];
    sre[q*LDW + t + 512] = rv[4*q+1];
    sim[q*LDW + t]       = rv[4*q+2];
    sim[q*LDW + t + 512] = rv[4*q+3];
  }
  __syncthreads();
  for (int s = 0; s < 10; ++s) {
    const int half = 1 << s;
    const int j    = t & (half - 1);
    const int ib   = ((t >> s) << (s + 1)) | j;
    const int ti2  = j << (9 - s);
    const float wc = twc[ti2], ws = tws[ti2];
    #pragma unroll
    for (int q = 0; q < 8; ++q) {
      float* pr = &sre[q*LDW]; float* pi = &sim[q*LDW];
      const float r1 = pr[ib],      i1v = pi[ib];
      const float r2 = pr[ib+half], i2v = pi[ib+half];
      const float tr = r2*wc - i2v*ws;
      const float ti = r2*ws + i2v*wc;
      pr[ib]      = r1 + tr; pi[ib]      = i1v + ti;
      pr[ib+half] = r1 - tr; pi[ib+half] = i1v - ti;
    }
    __syncthreads();
  }
  const int tx = t & 15, th = t >> 4;    // tx: real row 0..15, th 0..31
  const int q  = tx >> 1, par = tx & 1;
  #pragma unroll
  for (int hh = 0; hh < 17; ++hh) {
    const int h = hh*32 + th;
    if (h < HKEEP) {
      const int mh = (1024 - h) & 1023;
      const float zr = sre[q*LDW + h],  zi = sim[q*LDW + h];
      const float mr = sre[q*LDW + mh], mi = sim[q*LDW + mh];
      float orr, oii;
      if (par == 0) { orr = 0.5f*(zr + mr); oii = 0.5f*(zi - mi); }
      else          { orr = 0.5f*(zi + mi); oii = 0.5f*(mr - zr); }
      reT[(size_t)h*NROWS + row0 + tx] = (bf16_t)orr;
      imT[(size_t)h*NROWS + row0 + tx] = (bf16_t)oii;
    }
  }
}

// ---------------- 2048-pt FFT along s, one (h, batch) column per block; bf16 in/out.
__global__ __launch_bounds__(256) void fft_s_col(
    const bf16_t* __restrict__ reT, const bf16_t* __restrict__ imT,
    bf16_t* __restrict__ fTb)
{
  __shared__ float sre[2048], sim[2048], twc[1024], tws[1024];
  const int t = threadIdx.x;
  const int h = blockIdx.x;           // 0..512
  const int batch = blockIdx.y;       // 0..3
  const size_t base = (size_t)h * NROWS + batch * 2048;
  for (int k = t; k < 1024; k += 256) {
    float sv, cv; sincosf(-6.28318530717958647692f * (float)k * (1.0f/2048.0f), &sv, &cv);
    twc[k] = cv; tws[k] = sv;
  }
  #pragma unroll
  for (int q = 0; q < 8; ++q) {
    const int i = t + 256*q;
    const int src = __brev((unsigned)i) >> 21;   // 11-bit bit reversal
    sre[i] = (float)reT[base + src];
    sim[i] = (float)imT[base + src];
  }
  __syncthreads();
  for (int s = 0; s < 11; ++s) {
    const int half = 1 << s;
    #pragma unroll
    for (int q = 0; q < 4; ++q) {
      const int b  = t + 256*q;
      const int j  = b & (half - 1);
      const int ib = ((b >> s) << (s + 1)) | j;
      const int ti2 = j << (10 - s);
      const float wc = twc[ti2], ws = tws[ti2];
      const float r1 = sre[ib],       i1v = sim[ib];
      const float r2 = sre[ib+half],  i2v = sim[ib+half];
      const float tr = r2*wc - i2v*ws;
      const float ti = r2*ws + i2v*wc;
      sre[ib]      = r1 + tr; sim[ib]      = i1v + ti;
      sre[ib+half] = r1 - tr; sim[ib+half] = i1v - ti;
    }
    __syncthreads();
  }
  #pragma unroll
  for (int q = 0; q < 8; ++q) {
    const int i = t + 256*q;
    fTb[base + i] = (bf16_t)sre[i];
  }
}

// ---------------- fused: untranspose + Hermitian mirror + x residual + LN1 -> xn
#define FLD 1028   // padded row stride (f32)
__global__ __launch_bounds__(256) void fuse_umadd_ln1(
    const bf16_t* __restrict__ fTb, const float* __restrict__ x,
    const float* __restrict__ gw, const float* __restrict__ gb,
    bf16_t* __restrict__ xn)
{
  __shared__ float tile[16*FLD];
  __shared__ float mrow[16], vrow[16];
  const int t = threadIdx.x;
  const int r0 = blockIdx.x * 16;
  const int batch = r0 >> 11;            // 16 | 2048 -> uniform per block
  const int rl0 = r0 & 2047;             // s index of row 0 (block-uniform)
  #pragma unroll
  for (int c = 0; c < 4; ++c) {
    const int h = t + 256*c;             // 0..1023
    bf16_t vals[16];                     // vals[rb] = fourier term for row r0+rb
    if (h <= 512) {
      const bf16_t* src = fTb + (size_t)h*NROWS + r0;
      *(bf16x8*)&vals[0] = *(const bf16x8*)(src);
      *(bf16x8*)&vals[8] = *(const bf16x8*)(src + 8);
    } else {
      const int hm = 1024 - h;           // 1..511
      const bf16_t* base = fTb + (size_t)hm*NROWS + (batch << 11);
      if (rl0 == 0) {
        vals[0] = base[0];
        #pragma unroll
        for (int rb = 1; rb < 16; ++rb) vals[rb] = base[2048 - rb];
      } else {
        bf16_t tmp[16];
        *(bf16x8*)&tmp[0] = *(const bf16x8*)(base + (2048 - rl0 - 15));
        *(bf16x8*)&tmp[8] = *(const bf16x8*)(base + (2048 - rl0 - 7));
        #pragma unroll
        for (int rb = 0; rb < 16; ++rb) vals[rb] = tmp[15 - rb];
      }
    }
    #pragma unroll
    for (int rb = 0; rb < 16; ++rb)
      tile[rb*FLD + h] = (float)vals[rb];
  }
  __syncthreads();
  #pragma unroll
  for (int rr = 0; rr < 16; ++rr) {
    float4 xv = *(const float4*)(x + (size_t)(r0+rr)*HD + t*4);
    float4 tv = *(float4*)&tile[rr*FLD + t*4];
    tv.x += xv.x; tv.y += xv.y; tv.z += xv.z; tv.w += xv.w;
    *(float4*)&tile[rr*FLD + t*4] = tv;
  }
  __syncthreads();
  {
    const int r = t >> 4, i = t & 15;
    float s = 0.f, s2 = 0.f;
    #pragma unroll
    for (int k = 0; k < 64; ++k) {
      const float v = tile[r*FLD + i + 16*k];
      s += v; s2 += v*v;
    }
    #pragma unroll
    for (int o = 8; o > 0; o >>= 1) { s += __shfl_xor(s, o); s2 += __shfl_xor(s2, o); }
    if (i == 0) {
      const float mu = s * (1.0f/1024.0f);
      mrow[r] = mu;
      vrow[r] = rsqrtf(s2 * (1.0f/1024.0f) - mu*mu + 1e-5f);
    }
  }
  __syncthreads();
  const float4 wv = *(const float4*)(gw + t*4);
  const float4 bv = *(const float4*)(gb + t*4);
  #pragma unroll
  for (int rr = 0; rr < 16; ++rr) {
    const float mu = mrow[rr], rs = vrow[rr];
    float4 tv = *(float4*)&tile[rr*FLD + t*4];
    bf16x4 o;
    o[0] = (bf16_t)((tv.x-mu)*rs*wv.x + bv.x);
    o[1] = (bf16_t)((tv.y-mu)*rs*wv.y + bv.y);
    o[2] = (bf16_t)((tv.z-mu)*rs*wv.z + bv.z);
    o[3] = (bf16_t)((tv.w-mu)*rs*wv.w + bv.w);
    *(bf16x4*)(xn + (size_t)(r0+rr)*HD + t*4) = o;
  }
}

// ---------------- LayerNorm over H=1024, bf16 in, fp32 out (LN2)
__global__ __launch_bounds__(256) void layernorm_b2f(
    const bf16_t* __restrict__ in, const float* __restrict__ gw,
    const float* __restrict__ gb, float* __restrict__ of)
{
  __shared__ float red[8];
  const size_t row = blockIdx.x;
  const int t = threadIdx.x;
  bf16x4 v4 = *(const bf16x4*)(in + row*HD + t*4);
  const float vx = (float)v4[0], vy = (float)v4[1], vz = (float)v4[2], vw = (float)v4[3];
  float s = vx + vy + vz + vw;
  #pragma unroll
  for (int o = 32; o > 0; o >>= 1) s += __shfl_xor(s, o);
  if ((t & 63) == 0) red[t >> 6] = s;
  __syncthreads();
  const float mu = (red[0]+red[1]+red[2]+red[3]) * (1.0f/1024.0f);
  const float dx = vx-mu, dy = vy-mu, dz = vz-mu, dw = vw-mu;
  float sq = dx*dx + dy*dy + dz*dz + dw*dw;
  #pragma unroll
  for (int o = 32; o > 0; o >>= 1) sq += __shfl_xor(sq, o);
  if ((t & 63) == 0) red[4 + (t >> 6)] = sq;
  __syncthreads();
  const float var  = (red[4]+red[5]+red[6]+red[7]) * (1.0f/1024.0f);
  const float rstd = rsqrtf(var + 1e-5f);
  const float4 wv = *(const float4*)(gw + t*4);
  const float4 bv = *(const float4*)(gb + t*4);
  float4 o;
  o.x = dx*rstd*wv.x + bv.x;
  o.y = dy*rstd*wv.y + bv.y;
  o.z = dz*rstd*wv.z + bv.z;
  o.w = dw*rstd*wv.w + bv.w;
  *(float4*)(of + row*HD + t*4) = o;
}

// fast GELU (tanh form via exp2); |err| vs erf-GELU ~1e-3 << 0.1075 threshold
__device__ __forceinline__ float gelu_fast(float v) {
  const float u  = 0.7978845608028654f * v * (1.0f + 0.044715f * v * v);
  const float e  = exp2f(-2.8853900817779268f * u);   // exp(-2u)
  return v / (1.0f + e);                               // v * sigmoid(2u)
}

// ---------------- 8-phase 256x(NQ*128) bf16 MFMA GEMM.
// r19: UNPINNED phases - the explicit lgkmcnt(0)+sched_barrier(0) before the
// MFMA cluster is removed. Plain C++ ds_reads + builtin MFMA let the compiler
// emit fine-grained counted lgkmcnt per first-use (m97-style), overlapping the
// LDS drain tail with the MFMA cluster head. Reads ordered bq-first so the
// m=0 cluster's operands (bq + af[0]) complete earliest (DS completes in-order).
// Everything else identical to r14 (barriers, setprio, counted vmcnt @ p3/p7).
template <int NQ, bool GELU_OUT>
__global__ __launch_bounds__(512, 2) void gemm8r(
    const bf16_t* __restrict__ A,     // [M][K]
    const bf16_t* __restrict__ Bt,    // [N][K]
    const float*  __restrict__ bias,  // [N]
    const bf16_t* __restrict__ resid, // [M][N] (only when !GELU_OUT)
    bf16_t* __restrict__ outB,
    int M, int N, int K, int gx)
{
  __shared__ bf16_t As[2][2][128*64];
  __shared__ bf16_t Bs[2][2][NQ*64*64];

  const int tid  = threadIdx.x;
  const int wave = tid >> 6, lane = tid & 63;
  const int wr = wave >> 2, wc = wave & 3;   // 2x4 waves
  const int lr = lane & 15, lkg = lane >> 4;

  const int nwg = gridDim.x;
  const int sid = (blockIdx.x & 7) * (nwg >> 3) + (blockIdx.x >> 3);
  const int bx = sid % gx, by = sid / gx;
  const int brow = by * 256, bcol = bx * (NQ*128);

  const int rl = lane >> 3;                  // 0..7
  const int sg = (lane & 7) ^ rl;            // pre-swizzled source k-group

  auto stageA = [&](int b, int mh, int tt) {
    #pragma unroll
    for (int l = 0; l < 2; ++l) {
      const int row = brow + l*128 + mh*64 + wave*8 + rl;
      gload_lds16(A + (size_t)row * K + tt*64 + sg*8,
                  &As[b][mh][(l*64 + wave*8)*64]);
    }
  };
  auto stageB = [&](int b, int nh, int tt) {
    #pragma unroll
    for (int l = 0; l < NQ; ++l) {
      const int rho = l*64 + wave*8 + rl;
      const int wcs = rho / (NQ*16), r = rho % (NQ*16);
      const int row = bcol + wcs*(NQ*32) + nh*(NQ*16) + r;
      gload_lds16(Bt + (size_t)row * K + tt*64 + sg*8,
                  &Bs[b][nh][(l*64 + wave*8)*64]);
    }
  };

  f32x4 acc[8][2*NQ] = {};
  bf16x8 af[4][2];          // current A-half fragments
  bf16x8 bq[2][NQ][2];      // BOTH B-half fragments resident (NH static index)

  const int NT = K >> 6;
  const int NI = NT >> 1;
  constexpr int WT = (NQ==2) ? 6 : 4;   // counted wait: 3 stage-halves in flight

  #define PHASE(BUF, MH, NH, DOA, DOB, STG, DOW) do { \
    if constexpr (DOB) { \
      _Pragma("unroll") for (int n = 0; n < NQ; ++n) { \
      _Pragma("unroll") for (int ks = 0; ks < 2; ++ks) \
        bq[NH][n][ks] = *(const bf16x8*)&Bs[BUF][NH][(wc*(NQ*16) + n*16 + lr)*64 + (((lkg + ks*4) ^ (lr & 7)) << 3)]; } \
    } \
    if constexpr (DOA) { \
      _Pragma("unroll") for (int m = 0; m < 4; ++m) { \
      _Pragma("unroll") for (int ks = 0; ks < 2; ++ks) \
        af[m][ks] = *(const bf16x8*)&As[BUF][MH][(wr*64 + m*16 + lr)*64 + (((lkg + ks*4) ^ (lr & 7)) << 3)]; } \
    } \
    STG; \
    __builtin_amdgcn_s_barrier(); \
    __builtin_amdgcn_s_setprio(1); \
    _Pragma("unroll") for (int m = 0; m < 4; ++m) { \
    _Pragma("unroll") for (int n = 0; n < NQ; ++n) { \
    _Pragma("unroll") for (int ks = 0; ks < 2; ++ks) \
      acc[(MH)*4+m][(NH)*NQ+n] = __builtin_amdgcn_mfma_f32_16x16x32_bf16(bq[NH][n][ks], af[m][ks], acc[(MH)*4+m][(NH)*NQ+n], 0, 0, 0); } } \
    __builtin_amdgcn_s_setprio(0); \
    if constexpr (DOW) vmw<WT>(); \
    __builtin_amdgcn_s_barrier(); \
  } while (0)

  // prologue: buf0 tile0 (Bh0,Ah0,Bh1,Ah1) + buf1 tile1 (Bh0,Ah0,Bh1)
  stageB(0,0,0); stageA(0,0,0); stageB(0,1,0); stageA(0,1,0);
  stageB(1,0,1); stageA(1,0,1); stageB(1,1,1);
  vmw<WT>();
  __builtin_amdgcn_s_barrier();

  for (int j = 0; j < NI; ++j) {
    const int c1 = 2*j + 1;
    const int n2 = (2*j + 2 < NT) ? 2*j + 2 : NT - 1;
    const int n3 = (2*j + 3 < NT) ? 2*j + 3 : NT - 1;
    PHASE(0, 0, 0, 1, 1, stageA(1,1,c1), false);   // p0
    PHASE(0, 0, 1, 0, 1, stageB(0,0,n2), false);   // p1
    PHASE(0, 1, 1, 1, 0, stageA(0,0,n2), false);   // p2
    PHASE(0, 1, 0, 0, 0, stageB(0,1,n2), true);    // p3  vmcnt(WT)
    PHASE(1, 0, 0, 1, 1, stageA(0,1,n2), false);   // p4
    PHASE(1, 0, 1, 0, 1, stageB(1,0,n3), false);   // p5
    PHASE(1, 1, 1, 1, 0, stageA(1,0,n3), false);   // p6
    PHASE(1, 1, 0, 0, 0, stageB(1,1,n3), true);    // p7  vmcnt(WT)
  }
  #undef PHASE

  // epilogue
  #pragma unroll
  for (int im = 0; im < 8; ++im) {
    const int row = brow + wr*128 + (im >> 2)*64 + (im & 3)*16 + lr;
    #pragma unroll
    for (int in = 0; in < 2*NQ; ++in) {
      const int col = bcol + wc*(NQ*32) + (in/NQ)*(NQ*16) + (in%NQ)*16 + lkg*4;
      const float4 bv4 = *(const float4*)(bias + col);
      float v0 = acc[im][in][0] + bv4.x;
      float v1 = acc[im][in][1] + bv4.y;
      float v2 = acc[im][in][2] + bv4.z;
      float v3 = acc[im][in][3] + bv4.w;
      bf16x4 o;
      if constexpr (GELU_OUT) {
        o[0] = (bf16_t)gelu_fast(v0); o[1] = (bf16_t)gelu_fast(v1);
        o[2] = (bf16_t)gelu_fast(v2); o[3] = (bf16_t)gelu_fast(v3);
      } else {
        bf16x4 rr = *(const bf16x4*)(resid + (size_t)row * N + col);
        o[0] = (bf16_t)(v0 + (float)rr[0]); o[1] = (bf16_t)(v1 + (float)rr[1]);
        o[2] = (bf16_t)(v2 + (float)rr[2]); o[3] = (bf16_t)(v3 + (float)rr[3]);
      }
      *(bf16x4*)(outB + (size_t)row * N + col) = o;
    }
  }
}

extern "C" void kernel_launch(void* const* d_in, const int* in_sizes, int n_in,
                              void* d_out, int out_size, void* d_ws, size_t ws_size,
                              hipStream_t stream) {
  const float* x    = (const float*)d_in[0];
  const float* ln1w = (const float*)d_in[1];
  const float* ln1b = (const float*)d_in[2];
  const float* ln2w = (const float*)d_in[3];
  const float* ln2b = (const float*)d_in[4];
  const float* w1   = (const float*)d_in[5];
  const float* b1   = (const float*)d_in[6];
  const float* w2   = (const float*)d_in[7];
  const float* b2   = (const float*)d_in[8];
  float* out = (float*)d_out;

  // workspace (peak < 128 MB, lifetimes checked):
  //  w1b [0,8M)  w2b [8,16M)                         (all steps)
  //  reTb [16,25M)  imTb [26,35M)  (bf16)            (steps 2-3)
  //  fTb  [36,45M)  (bf16)                           (steps 3-4)
  //  xn  [99,115M)                                   (steps 4-6, GEMM2 resid)
  //  hg  [16,80M)  (reuses reTb/imTb/fTb, all dead)  (steps 5-6)
  //  z   [80,96M)  (bf16 pre-LN2)                    (steps 6-7)
  char* ws = (char*)d_ws;
  bf16_t* w1b  = (bf16_t*)(ws);
  bf16_t* w2b  = (bf16_t*)(ws + (8u   << 20));
  bf16_t* reTb = (bf16_t*)(ws + (16u  << 20));
  bf16_t* imTb = (bf16_t*)(ws + (26u  << 20));
  bf16_t* fTb  = (bf16_t*)(ws + (36u  << 20));
  bf16_t* xn   = (bf16_t*)(ws + (99u  << 20));
  bf16_t* hg   = (bf16_t*)(ws + (16u  << 20));
  bf16_t* z    = (bf16_t*)(ws + (80u  << 20));

  // 1. weight transposes + bf16 conversion
  transpose_to_bf16<<<dim3(DFF/32, HD/32), dim3(32, 8), 0, stream>>>(w1, w1b, HD, DFF);
  transpose_to_bf16<<<dim3(HD/32, DFF/32), dim3(32, 8), 0, stream>>>(w2, w2b, DFF, HD);

  // 2. pair-packed FFT along h + transposed truncated store (bf16)
  fft_h_t<<<NROWS/RPB, 512, 0, stream>>>(x, reTb, imTb);

  // 3. FFT along s per (h<=512, batch) column; real part out (bf16)
  fft_s_col<<<dim3(513, 4), 256, 0, stream>>>(reTb, imTb, fTb);

  // 4. fused untranspose + mirror + x residual + LN1 -> xn (bf16, vector gather)
  fuse_umadd_ln1<<<NROWS/16, 256, 0, stream>>>(fTb, x, ln1w, ln1b, xn);

  // 5./6. FFN: 8-phase GEMMs (unpinned phases); GEMM2 emits bf16 z
  gemm8r<2, true><<<(NROWS/256)*(DFF/256), 512, 0, stream>>>(
      xn, w1b, b1, nullptr, hg, NROWS, DFF, HD, DFF/256);
  gemm8r<1, false><<<(NROWS/256)*(HD/128), 512, 0, stream>>>(
      hg, w2b, b2, xn, z, NROWS, HD, DFF, HD/128);

  // 7. LN2: bf16 z -> fp32 out
  layernorm_b2f<<<NROWS, 256, 0, stream>>>(z, ln2w, ln2b, out);
}